// Round 7
// baseline (212.239 us; speedup 1.0000x reference)
//
#include <hip/hip_runtime.h>

// Problem constants (from reference): B=64 batches, grid 64^3, P=4096 points.
#define BB 64
#define NDIM 64
#define GRID3 (NDIM * NDIM * NDIM)   // 262144 bins per batch
#define NPTS 4096
#define NROWS (BB * NDIM * NDIM)     // 262144 rows of 64 bins (b, i0, i1)
#define CAP 32                        // list capacity per row; Poisson(1) -> P(>=32)~1e-36

// native clang vector type: __builtin_nontemporal_* requires it (HIP float4
// is a class and is rejected).
typedef float v4f __attribute__((ext_vector_type(4)));

// d_ws layout: [0, 1MB) u32 per-row counters; [1MB, 9MB) u8 lists (CAP/row).

// Kernel 1: visit each point once, push its i2 into the per-row list.
// Rows are (b, i0, i1): suffix-cumsum along i2 never mixes rows, so a
// per-row bin list is a complete sufficient statistic — the dense 64^3
// histogram intermediate (R2-R5's LDS phase + scan + barriers) disappears.
__global__ __launch_bounds__(256) void bin_kernel(const float* __restrict__ z,
                                                  unsigned int* __restrict__ cnt,
                                                  unsigned char* __restrict__ list) {
    int t = blockIdx.x * 256 + threadIdx.x;   // 0 .. BB*NPTS-1
    int b = t >> 12;
    const float* zp = z + (size_t)t * 3;
    float z0 = zp[0], z1 = zp[1], z2 = zp[2];
    int i0 = min(max((int)floorf(z0 * 64.0f), 0), 63);
    int i1 = min(max((int)floorf(z1 * 64.0f), 0), 63);
    int i2 = min(max((int)floorf(z2 * 64.0f), 0), 63);
    int rid = (b << 12) | (i0 << 6) | i1;
    unsigned int slot = atomicAdd(&cnt[rid], 1u);
    if (slot < CAP) list[(size_t)rid * CAP + slot] = (unsigned char)i2;
}

// Kernel 2: pure streaming output. No LDS, no barriers, no phases — the
// shape of the 85%-of-peak fill kernel. One thread per float4 quad of the
// output; suffix count computed by direct comparison against the row's
// point list (mean 1 point/row).
__global__ __launch_bounds__(256) void out_kernel(const float* __restrict__ x,
                                                  const unsigned int* __restrict__ cnt,
                                                  const unsigned char* __restrict__ list,
                                                  float* __restrict__ counts,
                                                  float* __restrict__ rm) {
    const v4f* x4 = (const v4f*)x;
    v4f* c4 = (v4f*)counts;
    v4f* r4 = (v4f*)rm;

    const int qb = blockIdx.x * 1024;          // block's quad chunk (64 rows)

    #pragma unroll
    for (int i = 0; i < 4; ++i) {
        int g   = qb + i * 256 + threadIdx.x;  // global quad index
        int row = g >> 4;                      // 16 quads per 64-bin row
        int q0  = (g & 15) << 2;               // first bin of this quad

        int n = min((int)cnt[row], CAP);       // same line for 16 lanes: broadcast

        v4f s = (v4f){0.f, 0.f, 0.f, 0.f};
        const unsigned char* lp = list + (size_t)row * CAP;
        for (int j = 0; j < n; ++j) {
            int bin = lp[j];
            s.x += (bin >= q0 + 0) ? 1.0f : 0.0f;
            s.y += (bin >= q0 + 1) ? 1.0f : 0.0f;
            s.z += (bin >= q0 + 2) ? 1.0f : 0.0f;
            s.w += (bin >= q0 + 3) ? 1.0f : 0.0f;
        }

        __builtin_nontemporal_store(s, &c4[g]);

        // s is non-increasing within the row, so s.x>0 predicates the quad.
        v4f r = (v4f){0.f, 0.f, 0.f, 0.f};
        if (s.x > 0.0f) {
            v4f xv = x4[g];
            r.x = (s.x > 0.0f) ? xv.x : 0.0f;
            r.y = (s.y > 0.0f) ? xv.y : 0.0f;
            r.z = (s.z > 0.0f) ? xv.z : 0.0f;
            r.w = (s.w > 0.0f) ? xv.w : 0.0f;
        }
        __builtin_nontemporal_store(r, &r4[g]);
    }
}

extern "C" void kernel_launch(void* const* d_in, const int* in_sizes, int n_in,
                              void* d_out, int out_size, void* d_ws, size_t ws_size,
                              hipStream_t stream) {
    const float* x = (const float*)d_in[0];   // [BB, 64,64,64]
    const float* z = (const float*)d_in[1];   // [BB, NPTS, 3]

    float* counts = (float*)d_out;                        // output 0
    float* rm     = counts + (size_t)BB * GRID3;          // output 1

    unsigned int*  cnt  = (unsigned int*)d_ws;                           // 1 MB
    unsigned char* list = (unsigned char*)d_ws + (size_t)NROWS * 4;      // 8 MB

    // zero the per-row counters (ws is poisoned 0xAA before every timed call)
    (void)hipMemsetAsync(cnt, 0, (size_t)NROWS * sizeof(unsigned int), stream);

    bin_kernel<<<(BB * NPTS) / 256, 256, 0, stream>>>(z, cnt, list);

    // 4,194,304 quads total, 1024 per block -> 4096 blocks
    out_kernel<<<(NROWS * 16) / 1024, 256, 0, stream>>>(x, cnt, list, counts, rm);
}

// Round 8
// 197.107 us; speedup vs baseline: 1.0768x; 1.0768x over previous
//
#include <hip/hip_runtime.h>

// Problem constants (from reference): B=64 batches, grid 64^3, P=4096 points.
#define BB 64
#define NDIM 64
#define GRID3 (NDIM * NDIM * NDIM)   // 262144 bins per batch
#define NPTS 4096
#define NROWS (BB * NDIM * NDIM)     // 262144 rows of 64 bins (b, i0, i1)
#define CAP 32                        // list capacity per row

// native clang vector type: __builtin_nontemporal_* requires it.
typedef float v4f __attribute__((ext_vector_type(4)));

// d_ws layout: [0, 1MB) u32 per-row counters; [1MB, 9MB) u8 lists (CAP/row).

// Kernel 1: visit each point once, push its i2 into the per-row (b,i0,i1) list.
__global__ __launch_bounds__(256) void bin_kernel(const float* __restrict__ z,
                                                  unsigned int* __restrict__ cnt,
                                                  unsigned char* __restrict__ list) {
    int t = blockIdx.x * 256 + threadIdx.x;   // 0 .. BB*NPTS-1
    int b = t >> 12;
    const float* zp = z + (size_t)t * 3;
    float z0 = zp[0], z1 = zp[1], z2 = zp[2];
    int i0 = min(max((int)floorf(z0 * 64.0f), 0), 63);
    int i1 = min(max((int)floorf(z1 * 64.0f), 0), 63);
    int i2 = min(max((int)floorf(z2 * 64.0f), 0), 63);
    int rid = (b << 12) | (i0 << 6) | i1;
    unsigned int slot = atomicAdd(&cnt[rid], 1u);
    if (slot < CAP) list[(size_t)rid * CAP + slot] = (unsigned char)i2;
}

// Kernel 2: streaming output, phase-batched to break the R7 dependency chain
// (cnt -> serial byte loads -> s -> x -> store). Phases:
//   A: 4 independent cnt loads
//   B: 4x 16-byte list loads into registers  ||  4 x-loads predicated on n>0
//   C: register-only suffix-count compute, NT stores
__global__ __launch_bounds__(256) void out_kernel(const float* __restrict__ x,
                                                  const unsigned int* __restrict__ cnt,
                                                  const unsigned char* __restrict__ list,
                                                  float* __restrict__ counts,
                                                  float* __restrict__ rm) {
    const v4f* x4 = (const v4f*)x;
    v4f* c4 = (v4f*)counts;
    v4f* r4 = (v4f*)rm;

    const int qb  = blockIdx.x * 1024;         // block's quad chunk
    const int tid = threadIdx.x;

    // Phase A: all row counts in flight
    int g[4], row[4], n[4];
    #pragma unroll
    for (int i = 0; i < 4; ++i) {
        g[i]   = qb + i * 256 + tid;           // global quad index
        row[i] = g[i] >> 4;                    // 16 quads per 64-bin row
        n[i]   = (int)cnt[row[i]];             // consecutive rows: coalesced
    }

    // Phase B1: first 16 list entries per row as two u64 register loads.
    // (P(n>16) ~ 7e-10 across the fixed dataset; guarded fallback below
    // keeps correctness unconditional. Bytes past n are garbage, unused.)
    unsigned long long l0[4], l1[4];
    #pragma unroll
    for (int i = 0; i < 4; ++i) {
        const unsigned long long* lp =
            (const unsigned long long*)(list + ((size_t)row[i] << 5));
        l0[i] = lp[0];
        l1[i] = lp[1];
    }

    // Phase B2: x loads depend only on Phase A (n>0), not on list bytes.
    v4f xv[4];
    #pragma unroll
    for (int i = 0; i < 4; ++i) {
        xv[i] = (v4f){0.f, 0.f, 0.f, 0.f};
        if (n[i] > 0) xv[i] = __builtin_nontemporal_load(&x4[g[i]]);
    }

    // Phase C: compute suffix counts from register bytes, store.
    #pragma unroll
    for (int i = 0; i < 4; ++i) {
        const int q0 = (g[i] & 15) << 2;       // first bin of this quad
        v4f s = (v4f){0.f, 0.f, 0.f, 0.f};

        const int m = min(n[i], 16);
        unsigned long long w = l0[i];
        for (int j = 0; j < m; ++j) {
            if (j == 8) w = l1[i];
            int bin = (int)(w & 0xFFu);
            w >>= 8;
            s.x += (bin >= q0 + 0) ? 1.0f : 0.0f;
            s.y += (bin >= q0 + 1) ? 1.0f : 0.0f;
            s.z += (bin >= q0 + 2) ? 1.0f : 0.0f;
            s.w += (bin >= q0 + 3) ? 1.0f : 0.0f;
        }
        if (n[i] > 16) {                       // cold fallback, ~never taken
            const unsigned char* lp = list + ((size_t)row[i] << 5);
            int e = min(n[i], CAP);
            for (int j = 16; j < e; ++j) {
                int bin = lp[j];
                s.x += (bin >= q0 + 0) ? 1.0f : 0.0f;
                s.y += (bin >= q0 + 1) ? 1.0f : 0.0f;
                s.z += (bin >= q0 + 2) ? 1.0f : 0.0f;
                s.w += (bin >= q0 + 3) ? 1.0f : 0.0f;
            }
        }

        __builtin_nontemporal_store(s, &c4[g[i]]);

        v4f r;
        r.x = (s.x > 0.0f) ? xv[i].x : 0.0f;
        r.y = (s.y > 0.0f) ? xv[i].y : 0.0f;
        r.z = (s.z > 0.0f) ? xv[i].z : 0.0f;
        r.w = (s.w > 0.0f) ? xv[i].w : 0.0f;
        __builtin_nontemporal_store(r, &r4[g[i]]);
    }
}

extern "C" void kernel_launch(void* const* d_in, const int* in_sizes, int n_in,
                              void* d_out, int out_size, void* d_ws, size_t ws_size,
                              hipStream_t stream) {
    const float* x = (const float*)d_in[0];   // [BB, 64,64,64]
    const float* z = (const float*)d_in[1];   // [BB, NPTS, 3]

    float* counts = (float*)d_out;                        // output 0
    float* rm     = counts + (size_t)BB * GRID3;          // output 1

    unsigned int*  cnt  = (unsigned int*)d_ws;                           // 1 MB
    unsigned char* list = (unsigned char*)d_ws + (size_t)NROWS * 4;      // 8 MB

    // zero the per-row counters (ws is poisoned 0xAA before every timed call)
    (void)hipMemsetAsync(cnt, 0, (size_t)NROWS * sizeof(unsigned int), stream);

    bin_kernel<<<(BB * NPTS) / 256, 256, 0, stream>>>(z, cnt, list);

    // 4,194,304 quads total, 1024 per block -> 4096 blocks
    out_kernel<<<(NROWS * 16) / 1024, 256, 0, stream>>>(x, cnt, list, counts, rm);
}